// Round 1
// baseline (3350.996 us; speedup 1.0000x reference)
//
#include <hip/hip_runtime.h>

#define N_NODES  50000
#define N_EDGES  800000
#define DIM      96
#define N_GRAPHS 128
#define OUT_DIM  10

// ---------------------------------------------------------------------------
// Fused node-level GEMM: acc = h @ W1 (self part, also serves as the scatter
// accumulator init), t2 = h @ W2 (message transform).
// Block (24,8) = 192 threads; block covers 32 nodes; each thread computes
// 4 nodes x 8 cols (2 float4) for BOTH matrices. RELU template applies
// relu on the h read (h buffers are stored pre-relu).
// ---------------------------------------------------------------------------
template <bool RELU>
__global__ __launch_bounds__(192) void gemm_node(
    const float* __restrict__ h, const float* __restrict__ W1,
    const float* __restrict__ W2, float* __restrict__ acc,
    float* __restrict__ t2)
{
    const int tx  = threadIdx.x;          // 0..23  -> float4 column
    const int ty  = threadIdx.y;          // 0..7
    const int col = tx * 4;
    const int nodeBase = blockIdx.x * 32 + ty;   // nodes: nodeBase + 8*i

    float4 a1[4], a2[4];
#pragma unroll
    for (int i = 0; i < 4; i++) {
        a1[i] = make_float4(0.f, 0.f, 0.f, 0.f);
        a2[i] = make_float4(0.f, 0.f, 0.f, 0.f);
    }

    int  nIdx[4];
    bool valid[4];
#pragma unroll
    for (int i = 0; i < 4; i++) {
        nIdx[i]  = nodeBase + 8 * i;
        valid[i] = nIdx[i] < N_NODES;
    }

    for (int k = 0; k < DIM; k += 4) {
        float4 hv[4];
#pragma unroll
        for (int i = 0; i < 4; i++) {
            if (valid[i]) {
                hv[i] = *(const float4*)(h + (size_t)nIdx[i] * DIM + k);
                if (RELU) {
                    hv[i].x = fmaxf(hv[i].x, 0.f);
                    hv[i].y = fmaxf(hv[i].y, 0.f);
                    hv[i].z = fmaxf(hv[i].z, 0.f);
                    hv[i].w = fmaxf(hv[i].w, 0.f);
                }
            } else {
                hv[i] = make_float4(0.f, 0.f, 0.f, 0.f);
            }
        }
#pragma unroll
        for (int j = 0; j < 4; j++) {
            const float4 w1 = *(const float4*)(W1 + (size_t)(k + j) * DIM + col);
            const float4 w2 = *(const float4*)(W2 + (size_t)(k + j) * DIM + col);
#pragma unroll
            for (int i = 0; i < 4; i++) {
                const float hj = (&hv[i].x)[j];
                a1[i].x += hj * w1.x; a1[i].y += hj * w1.y;
                a1[i].z += hj * w1.z; a1[i].w += hj * w1.w;
                a2[i].x += hj * w2.x; a2[i].y += hj * w2.y;
                a2[i].z += hj * w2.z; a2[i].w += hj * w2.w;
            }
        }
    }

#pragma unroll
    for (int i = 0; i < 4; i++) {
        if (valid[i]) {
            *(float4*)(acc + (size_t)nIdx[i] * DIM + col) = a1[i];
            *(float4*)(t2  + (size_t)nIdx[i] * DIM + col) = a2[i];
        }
    }
}

// ---------------------------------------------------------------------------
// Edge scatter: acc[dst] += t2[src].  One thread per (edge, float4-chunk);
// 24 chunks cover the 96-float row.  unsafeAtomicAdd -> HW global_atomic_add_f32.
// ---------------------------------------------------------------------------
__global__ __launch_bounds__(256) void scatter_edges(
    const float* __restrict__ t2, const int* __restrict__ src,
    const int* __restrict__ dst, float* __restrict__ acc)
{
    const int tid = blockIdx.x * 256 + threadIdx.x;   // grid sized exactly
    const int e   = tid / 24;
    const int c   = (tid - e * 24) * 4;

    const int s = src[e];
    const int d = dst[e];

    const float4 v = *(const float4*)(t2 + (size_t)s * DIM + c);
    float* p = acc + (size_t)d * DIM + c;
    unsafeAtomicAdd(p + 0, v.x);
    unsafeAtomicAdd(p + 1, v.y);
    unsafeAtomicAdd(p + 2, v.z);
    unsafeAtomicAdd(p + 3, v.w);
}

// ---------------------------------------------------------------------------
// Graph pooling: batch is sorted, so each graph is a contiguous node range.
// One block per graph; binary-search the range; relu applied on read
// (h buffer is pre-relu).  Pure writes, no atomics, no init needed.
// ---------------------------------------------------------------------------
__global__ __launch_bounds__(384) void pool_graphs(
    const float* __restrict__ h, const int* __restrict__ batch,
    float* __restrict__ gemb)
{
    const int g = blockIdx.x;

    int lo = 0, hi = N_NODES;
    while (lo < hi) { int m = (lo + hi) >> 1; if (batch[m] < g) lo = m + 1; else hi = m; }
    const int start = lo;
    hi = N_NODES;
    while (lo < hi) { int m = (lo + hi) >> 1; if (batch[m] < g + 1) lo = m + 1; else hi = m; }
    const int end = lo;

    const int col = threadIdx.x;   // 0..95
    const int ty  = threadIdx.y;   // 0..3
    float s = 0.f;
    for (int n = start + ty; n < end; n += 4)
        s += fmaxf(h[(size_t)n * DIM + col], 0.f);

    __shared__ float part[4][DIM];
    part[ty][col] = s;
    __syncthreads();
    if (ty == 0)
        gemb[g * DIM + col] = part[0][col] + part[1][col] + part[2][col] + part[3][col];
}

// ---------------------------------------------------------------------------
// Classifier head: hidden = relu(gemb @ cw1 + cb1); out = hidden @ cw2 + cb2.
// One block per graph.
// ---------------------------------------------------------------------------
__global__ __launch_bounds__(128) void classify(
    const float* __restrict__ gemb, const float* __restrict__ cw1,
    const float* __restrict__ cb1,  const float* __restrict__ cw2,
    const float* __restrict__ cb2,  float* __restrict__ out)
{
    const int g = blockIdx.x;
    const int t = threadIdx.x;

    __shared__ float gr[DIM];
    __shared__ float hid[DIM];

    if (t < DIM) gr[t] = gemb[g * DIM + t];
    __syncthreads();

    if (t < DIM) {
        float s = cb1[t];
#pragma unroll 4
        for (int k = 0; k < DIM; k++) s += gr[k] * cw1[k * DIM + t];
        hid[t] = fmaxf(s, 0.f);
    }
    __syncthreads();

    if (t < OUT_DIM) {
        float o = cb2[t];
#pragma unroll 4
        for (int k = 0; k < DIM; k++) o += hid[k] * cw2[k * OUT_DIM + t];
        out[g * OUT_DIM + t] = o;
    }
}

// ---------------------------------------------------------------------------
extern "C" void kernel_launch(void* const* d_in, const int* in_sizes, int n_in,
                              void* d_out, int out_size, void* d_ws, size_t ws_size,
                              hipStream_t stream)
{
    const float* x     = (const float*)d_in[0];
    const int*   ei    = (const int*)  d_in[1];
    const int*   batch = (const int*)  d_in[2];
    const float* W1    = (const float*)d_in[3];
    const float* W2    = (const float*)d_in[4];
    const float* cw1   = (const float*)d_in[5];
    const float* cb1   = (const float*)d_in[6];
    const float* cw2   = (const float*)d_in[7];
    const float* cb2   = (const float*)d_in[8];
    float*       out   = (float*)d_out;

    const int* src = ei;             // edge_index[0]
    const int* dst = ei + N_EDGES;   // edge_index[1]

    // workspace layout: 3 node buffers (ping-pong acc + t2) + graph embeddings
    float* bufA = (float*)d_ws;
    float* bufB = bufA + (size_t)N_NODES * DIM;
    float* bufT = bufB + (size_t)N_NODES * DIM;
    float* gemb = bufT + (size_t)N_NODES * DIM;

    const dim3 gblk(24, 8);
    const int  gGrid = (N_NODES + 31) / 32;          // 1563
    const int  sGrid = (N_EDGES * 24) / 256;         // 75000 (exact)

    const float* hin  = x;      // layer input (pre-relu except layer 0 = x)
    float*       accb = bufA;

    for (int l = 0; l < 3; l++) {
        const float* w1l = W1 + (size_t)l * DIM * DIM;
        const float* w2l = W2 + (size_t)l * DIM * DIM;
        if (l == 0)
            gemm_node<false><<<gGrid, gblk, 0, stream>>>(hin, w1l, w2l, accb, bufT);
        else
            gemm_node<true ><<<gGrid, gblk, 0, stream>>>(hin, w1l, w2l, accb, bufT);

        scatter_edges<<<sGrid, 256, 0, stream>>>(bufT, src, dst, accb);

        hin  = accb;                       // pre-relu; consumers apply relu on read
        accb = (accb == bufA) ? bufB : bufA;
    }

    pool_graphs<<<N_GRAPHS, dim3(96, 4), 0, stream>>>(hin, batch, gemb);
    classify<<<N_GRAPHS, 128, 0, stream>>>(gemb, cw1, cb1, cw2, cb2, out);
}

// Round 2
// 686.086 us; speedup vs baseline: 4.8842x; 4.8842x over previous
//
#include <hip/hip_runtime.h>

#define N_NODES  50000
#define N_EDGES  800000
#define DIM      96
#define N_GRAPHS 128
#define OUT_DIM  10

// ---------------------------------------------------------------------------
// Fused node-level GEMM: self = h @ W1, t2 = h @ W2.
// Block (24,8) = 192 threads; covers 32 nodes; each thread computes
// 4 nodes x 8 cols (2 float4) for BOTH matrices. RELU applies on the h read
// (h buffers are stored pre-relu).
// ---------------------------------------------------------------------------
template <bool RELU>
__global__ __launch_bounds__(192) void gemm_node(
    const float* __restrict__ h, const float* __restrict__ W1,
    const float* __restrict__ W2, float* __restrict__ self,
    float* __restrict__ t2)
{
    const int tx  = threadIdx.x;          // 0..23  -> float4 column
    const int ty  = threadIdx.y;          // 0..7
    const int col = tx * 4;
    const int nodeBase = blockIdx.x * 32 + ty;   // nodes: nodeBase + 8*i

    float4 a1[4], a2[4];
#pragma unroll
    for (int i = 0; i < 4; i++) {
        a1[i] = make_float4(0.f, 0.f, 0.f, 0.f);
        a2[i] = make_float4(0.f, 0.f, 0.f, 0.f);
    }

    int  nIdx[4];
    bool valid[4];
#pragma unroll
    for (int i = 0; i < 4; i++) {
        nIdx[i]  = nodeBase + 8 * i;
        valid[i] = nIdx[i] < N_NODES;
    }

    for (int k = 0; k < DIM; k += 4) {
        float4 hv[4];
#pragma unroll
        for (int i = 0; i < 4; i++) {
            if (valid[i]) {
                hv[i] = *(const float4*)(h + (size_t)nIdx[i] * DIM + k);
                if (RELU) {
                    hv[i].x = fmaxf(hv[i].x, 0.f);
                    hv[i].y = fmaxf(hv[i].y, 0.f);
                    hv[i].z = fmaxf(hv[i].z, 0.f);
                    hv[i].w = fmaxf(hv[i].w, 0.f);
                }
            } else {
                hv[i] = make_float4(0.f, 0.f, 0.f, 0.f);
            }
        }
#pragma unroll
        for (int j = 0; j < 4; j++) {
            const float4 w1 = *(const float4*)(W1 + (size_t)(k + j) * DIM + col);
            const float4 w2 = *(const float4*)(W2 + (size_t)(k + j) * DIM + col);
#pragma unroll
            for (int i = 0; i < 4; i++) {
                const float hj = (&hv[i].x)[j];
                a1[i].x += hj * w1.x; a1[i].y += hj * w1.y;
                a1[i].z += hj * w1.z; a1[i].w += hj * w1.w;
                a2[i].x += hj * w2.x; a2[i].y += hj * w2.y;
                a2[i].z += hj * w2.z; a2[i].w += hj * w2.w;
            }
        }
    }

#pragma unroll
    for (int i = 0; i < 4; i++) {
        if (valid[i]) {
            *(float4*)(self + (size_t)nIdx[i] * DIM + col) = a1[i];
            *(float4*)(t2   + (size_t)nIdx[i] * DIM + col) = a2[i];
        }
    }
}

// ---------------------------------------------------------------------------
// CSR build (by destination).  Rebuilt every launch (d_ws is re-poisoned).
// ---------------------------------------------------------------------------
__global__ __launch_bounds__(256) void zero_deg(int* __restrict__ deg)
{
    const int i = blockIdx.x * 256 + threadIdx.x;
    if (i < N_NODES) deg[i] = 0;
}

__global__ __launch_bounds__(256) void hist_dst(const int* __restrict__ dst,
                                                int* __restrict__ deg)
{
    const int e = blockIdx.x * 256 + threadIdx.x;
    if (e < N_EDGES) atomicAdd(&deg[dst[e]], 1);
}

// Single-block exclusive scan over 50000 degrees -> rowptr[50001] (+cursor copy).
__global__ __launch_bounds__(1024) void scan_deg(const int* __restrict__ deg,
                                                 int* __restrict__ rowptr,
                                                 int* __restrict__ cursor)
{
    __shared__ int buf[2][1024];
    const int t  = threadIdx.x;
    const int CH = (N_NODES + 1023) / 1024;       // 49
    const int b0 = t * CH;
    const int b1 = min(b0 + CH, N_NODES);

    int s = 0;
    for (int i = b0; i < b1; i++) s += deg[i];
    buf[0][t] = s;
    __syncthreads();

    int cur = 0;
    for (int off = 1; off < 1024; off <<= 1) {    // Hillis-Steele inclusive
        int v = buf[cur][t];
        if (t >= off) v += buf[cur][t - off];
        buf[cur ^ 1][t] = v;
        __syncthreads();
        cur ^= 1;
    }

    int excl = (t == 0) ? 0 : buf[cur][t - 1];
    for (int i = b0; i < b1; i++) {
        rowptr[i] = excl; cursor[i] = excl; excl += deg[i];
    }
    if (t == 1023) rowptr[N_NODES] = excl;        // total = prefix through 1022 (sums[1023]=0)
}

__global__ __launch_bounds__(256) void fill_csr(const int* __restrict__ src,
                                                const int* __restrict__ dst,
                                                int* __restrict__ cursor,
                                                int* __restrict__ csrc)
{
    const int e = blockIdx.x * 256 + threadIdx.x;
    if (e < N_EDGES) {
        const int pos = atomicAdd(&cursor[dst[e]], 1);
        csrc[pos] = src[e];
    }
}

// ---------------------------------------------------------------------------
// Pull-based aggregation: self[n] += sum_{s in inNbrs(n)} t2[s].  In-place on
// the self buffer (each thread owns its 4 floats).  Block (24,8): 8 nodes per
// block, 24 threads (one float4 column each) per node -> full-row coalesced
// reads of t2.  Zero atomics.
// ---------------------------------------------------------------------------
__global__ __launch_bounds__(192) void gather_nodes(
    const float* __restrict__ t2, const int* __restrict__ rowptr,
    const int* __restrict__ csrc, float* __restrict__ self)
{
    const int tx   = threadIdx.x;         // 0..23
    const int ty   = threadIdx.y;         // 0..7
    const int node = blockIdx.x * 8 + ty; // grid sized exactly: 6250*8 = 50000
    const int col  = tx * 4;

    const int r0 = rowptr[node];
    const int r1 = rowptr[node + 1];

    float4 a = *(const float4*)(self + (size_t)node * DIM + col);

    int j = r0;
    for (; j + 1 < r1; j += 2) {
        const int s0 = csrc[j];
        const int s1 = csrc[j + 1];
        const float4 v0 = *(const float4*)(t2 + (size_t)s0 * DIM + col);
        const float4 v1 = *(const float4*)(t2 + (size_t)s1 * DIM + col);
        a.x += v0.x; a.y += v0.y; a.z += v0.z; a.w += v0.w;
        a.x += v1.x; a.y += v1.y; a.z += v1.z; a.w += v1.w;
    }
    if (j < r1) {
        const int s0 = csrc[j];
        const float4 v0 = *(const float4*)(t2 + (size_t)s0 * DIM + col);
        a.x += v0.x; a.y += v0.y; a.z += v0.z; a.w += v0.w;
    }

    *(float4*)(self + (size_t)node * DIM + col) = a;
}

// ---------------------------------------------------------------------------
// Graph pooling: batch is sorted -> contiguous ranges; relu applied on read.
// ---------------------------------------------------------------------------
__global__ __launch_bounds__(384) void pool_graphs(
    const float* __restrict__ h, const int* __restrict__ batch,
    float* __restrict__ gemb)
{
    const int g = blockIdx.x;

    int lo = 0, hi = N_NODES;
    while (lo < hi) { int m = (lo + hi) >> 1; if (batch[m] < g) lo = m + 1; else hi = m; }
    const int start = lo;
    hi = N_NODES;
    while (lo < hi) { int m = (lo + hi) >> 1; if (batch[m] < g + 1) lo = m + 1; else hi = m; }
    const int end = lo;

    const int col = threadIdx.x;   // 0..95
    const int ty  = threadIdx.y;   // 0..3
    float s = 0.f;
    for (int n = start + ty; n < end; n += 4)
        s += fmaxf(h[(size_t)n * DIM + col], 0.f);

    __shared__ float part[4][DIM];
    part[ty][col] = s;
    __syncthreads();
    if (ty == 0)
        gemb[g * DIM + col] = part[0][col] + part[1][col] + part[2][col] + part[3][col];
}

// ---------------------------------------------------------------------------
// Classifier head.
// ---------------------------------------------------------------------------
__global__ __launch_bounds__(128) void classify(
    const float* __restrict__ gemb, const float* __restrict__ cw1,
    const float* __restrict__ cb1,  const float* __restrict__ cw2,
    const float* __restrict__ cb2,  float* __restrict__ out)
{
    const int g = blockIdx.x;
    const int t = threadIdx.x;

    __shared__ float gr[DIM];
    __shared__ float hid[DIM];

    if (t < DIM) gr[t] = gemb[g * DIM + t];
    __syncthreads();

    if (t < DIM) {
        float s = cb1[t];
#pragma unroll 4
        for (int k = 0; k < DIM; k++) s += gr[k] * cw1[k * DIM + t];
        hid[t] = fmaxf(s, 0.f);
    }
    __syncthreads();

    if (t < OUT_DIM) {
        float o = cb2[t];
#pragma unroll 4
        for (int k = 0; k < DIM; k++) o += hid[k] * cw2[k * OUT_DIM + t];
        out[g * OUT_DIM + t] = o;
    }
}

// ---------------------------------------------------------------------------
extern "C" void kernel_launch(void* const* d_in, const int* in_sizes, int n_in,
                              void* d_out, int out_size, void* d_ws, size_t ws_size,
                              hipStream_t stream)
{
    const float* x     = (const float*)d_in[0];
    const int*   ei    = (const int*)  d_in[1];
    const int*   batch = (const int*)  d_in[2];
    const float* W1    = (const float*)d_in[3];
    const float* W2    = (const float*)d_in[4];
    const float* cw1   = (const float*)d_in[5];
    const float* cb1   = (const float*)d_in[6];
    const float* cw2   = (const float*)d_in[7];
    const float* cb2   = (const float*)d_in[8];
    float*       out   = (float*)d_out;

    const int* src = ei;             // edge_index[0]
    const int* dst = ei + N_EDGES;   // edge_index[1]

    // workspace layout
    float* bufA = (float*)d_ws;                       // self/h ping
    float* bufB = bufA + (size_t)N_NODES * DIM;       // self/h pong
    float* bufT = bufB + (size_t)N_NODES * DIM;       // t2 scratch
    float* gemb = bufT + (size_t)N_NODES * DIM;       // [G, D]
    int*   deg    = (int*)(gemb + (size_t)N_GRAPHS * DIM);
    int*   rowptr = deg + N_NODES;                    // [N+1]
    int*   cursor = rowptr + (N_NODES + 1);           // [N]
    int*   csrc   = cursor + N_NODES;                 // [E]

    // ---- CSR build (once per launch; reused by all 3 layers) ----
    zero_deg<<<(N_NODES + 255) / 256, 256, 0, stream>>>(deg);
    hist_dst<<<N_EDGES / 256, 256, 0, stream>>>(dst, deg);
    scan_deg<<<1, 1024, 0, stream>>>(deg, rowptr, cursor);
    fill_csr<<<N_EDGES / 256, 256, 0, stream>>>(src, dst, cursor, csrc);

    const dim3 gblk(24, 8);
    const int  gGrid  = (N_NODES + 31) / 32;          // 1563
    const int  aGrid  = N_NODES / 8;                  // 6250 (exact)

    const float* hin  = x;      // pre-relu except layer 0 = x
    float*       selb = bufA;

    for (int l = 0; l < 3; l++) {
        const float* w1l = W1 + (size_t)l * DIM * DIM;
        const float* w2l = W2 + (size_t)l * DIM * DIM;
        if (l == 0)
            gemm_node<false><<<gGrid, gblk, 0, stream>>>(hin, w1l, w2l, selb, bufT);
        else
            gemm_node<true ><<<gGrid, gblk, 0, stream>>>(hin, w1l, w2l, selb, bufT);

        gather_nodes<<<aGrid, gblk, 0, stream>>>(bufT, rowptr, csrc, selb);

        hin  = selb;                       // pre-relu; consumers relu on read
        selb = (selb == bufA) ? bufB : bufA;
    }

    pool_graphs<<<N_GRAPHS, dim3(96, 4), 0, stream>>>(hin, batch, gemb);
    classify<<<N_GRAPHS, 128, 0, stream>>>(gemb, cw1, cb1, cw2, cb2, out);
}

// Round 3
// 590.269 us; speedup vs baseline: 5.6771x; 1.1623x over previous
//
#include <hip/hip_runtime.h>

#define N_NODES  50000
#define N_EDGES  800000
#define DIM      96
#define N_GRAPHS 128
#define OUT_DIM  10
#define SCAN_NB  ((N_NODES + 255) / 256)   // 196 blocks for the degree scan

// ---------------------------------------------------------------------------
// Fused node-level GEMM: self = h @ W1, t2 = h @ W2.
// Block (24,8) = 192 threads; covers 32 nodes; each thread computes
// 4 nodes x 8 cols (2 float4) for BOTH matrices. RELU applies on the h read
// (h buffers are stored pre-relu).
// ---------------------------------------------------------------------------
template <bool RELU>
__global__ __launch_bounds__(192) void gemm_node(
    const float* __restrict__ h, const float* __restrict__ W1,
    const float* __restrict__ W2, float* __restrict__ self,
    float* __restrict__ t2)
{
    const int tx  = threadIdx.x;          // 0..23  -> float4 column
    const int ty  = threadIdx.y;          // 0..7
    const int col = tx * 4;
    const int nodeBase = blockIdx.x * 32 + ty;   // nodes: nodeBase + 8*i

    float4 a1[4], a2[4];
#pragma unroll
    for (int i = 0; i < 4; i++) {
        a1[i] = make_float4(0.f, 0.f, 0.f, 0.f);
        a2[i] = make_float4(0.f, 0.f, 0.f, 0.f);
    }

    int  nIdx[4];
    bool valid[4];
#pragma unroll
    for (int i = 0; i < 4; i++) {
        nIdx[i]  = nodeBase + 8 * i;
        valid[i] = nIdx[i] < N_NODES;
    }

    for (int k = 0; k < DIM; k += 4) {
        float4 hv[4];
#pragma unroll
        for (int i = 0; i < 4; i++) {
            if (valid[i]) {
                hv[i] = *(const float4*)(h + (size_t)nIdx[i] * DIM + k);
                if (RELU) {
                    hv[i].x = fmaxf(hv[i].x, 0.f);
                    hv[i].y = fmaxf(hv[i].y, 0.f);
                    hv[i].z = fmaxf(hv[i].z, 0.f);
                    hv[i].w = fmaxf(hv[i].w, 0.f);
                }
            } else {
                hv[i] = make_float4(0.f, 0.f, 0.f, 0.f);
            }
        }
#pragma unroll
        for (int j = 0; j < 4; j++) {
            const float4 w1 = *(const float4*)(W1 + (size_t)(k + j) * DIM + col);
            const float4 w2 = *(const float4*)(W2 + (size_t)(k + j) * DIM + col);
#pragma unroll
            for (int i = 0; i < 4; i++) {
                const float hj = (&hv[i].x)[j];
                a1[i].x += hj * w1.x; a1[i].y += hj * w1.y;
                a1[i].z += hj * w1.z; a1[i].w += hj * w1.w;
                a2[i].x += hj * w2.x; a2[i].y += hj * w2.y;
                a2[i].z += hj * w2.z; a2[i].w += hj * w2.w;
            }
        }
    }

#pragma unroll
    for (int i = 0; i < 4; i++) {
        if (valid[i]) {
            *(float4*)(self + (size_t)nIdx[i] * DIM + col) = a1[i];
            *(float4*)(t2   + (size_t)nIdx[i] * DIM + col) = a2[i];
        }
    }
}

// ---------------------------------------------------------------------------
// CSR build (by destination).  Rebuilt every launch (d_ws is re-poisoned).
// ---------------------------------------------------------------------------
__global__ __launch_bounds__(256) void zero_deg(int* __restrict__ deg)
{
    const int i = blockIdx.x * 256 + threadIdx.x;
    if (i < N_NODES) deg[i] = 0;
}

__global__ __launch_bounds__(256) void hist_dst(const int* __restrict__ dst,
                                                int* __restrict__ deg)
{
    const int e = blockIdx.x * 256 + threadIdx.x;
    if (e < N_EDGES) atomicAdd(&deg[dst[e]], 1);
}

// ---- 3-phase parallel exclusive scan of deg[50000] -> rowptr/cursor --------
// Phase A: per-block (256 elems) sum -> bsum[SCAN_NB]
__global__ __launch_bounds__(256) void scan_phase_a(const int* __restrict__ deg,
                                                    int* __restrict__ bsum)
{
    const int i = blockIdx.x * 256 + threadIdx.x;
    int v = (i < N_NODES) ? deg[i] : 0;
#pragma unroll
    for (int off = 32; off > 0; off >>= 1) v += __shfl_down(v, off, 64);
    __shared__ int ws[4];
    if ((threadIdx.x & 63) == 0) ws[threadIdx.x >> 6] = v;
    __syncthreads();
    if (threadIdx.x == 0) bsum[blockIdx.x] = ws[0] + ws[1] + ws[2] + ws[3];
}

// Phase B: single block scans the SCAN_NB (=196) block sums in-place
// (bsum becomes exclusive block offsets) and writes rowptr[N_NODES] = total.
__global__ __launch_bounds__(256) void scan_phase_b(int* __restrict__ bsum,
                                                    int* __restrict__ rowptr)
{
    __shared__ int buf[2][256];
    const int t = threadIdx.x;
    int v = (t < SCAN_NB) ? bsum[t] : 0;
    buf[0][t] = v;
    __syncthreads();
    int cur = 0;
#pragma unroll
    for (int off = 1; off < 256; off <<= 1) {
        int x = buf[cur][t];
        if (t >= off) x += buf[cur][t - off];
        buf[cur ^ 1][t] = x;
        __syncthreads();
        cur ^= 1;
    }
    if (t < SCAN_NB) bsum[t] = (t == 0) ? 0 : buf[cur][t - 1];
    if (t == SCAN_NB - 1) rowptr[N_NODES] = buf[cur][SCAN_NB - 1];
}

// Phase C: block-local exclusive scan + block offset -> rowptr/cursor.
__global__ __launch_bounds__(256) void scan_phase_c(const int* __restrict__ deg,
                                                    const int* __restrict__ bsum,
                                                    int* __restrict__ rowptr,
                                                    int* __restrict__ cursor)
{
    __shared__ int buf[2][256];
    const int i = blockIdx.x * 256 + threadIdx.x;
    const int t = threadIdx.x;
    int v = (i < N_NODES) ? deg[i] : 0;
    buf[0][t] = v;
    __syncthreads();
    int cur = 0;
#pragma unroll
    for (int off = 1; off < 256; off <<= 1) {
        int x = buf[cur][t];
        if (t >= off) x += buf[cur][t - off];
        buf[cur ^ 1][t] = x;
        __syncthreads();
        cur ^= 1;
    }
    if (i < N_NODES) {
        const int excl = bsum[blockIdx.x] + ((t == 0) ? 0 : buf[cur][t - 1]);
        rowptr[i] = excl;
        cursor[i] = excl;
    }
}

__global__ __launch_bounds__(256) void fill_csr(const int* __restrict__ src,
                                                const int* __restrict__ dst,
                                                int* __restrict__ cursor,
                                                int* __restrict__ csrc)
{
    const int e = blockIdx.x * 256 + threadIdx.x;
    if (e < N_EDGES) {
        const int pos = atomicAdd(&cursor[dst[e]], 1);
        csrc[pos] = src[e];
    }
}

// ---------------------------------------------------------------------------
// Pull-based aggregation: self[n] += sum_{s in inNbrs(n)} t2[s].  In-place on
// the self buffer.  Block (24,8): 8 nodes per block, 24 threads (one float4
// column each) per node -> full-row coalesced reads of t2.  Zero atomics.
// ---------------------------------------------------------------------------
__global__ __launch_bounds__(192) void gather_nodes(
    const float* __restrict__ t2, const int* __restrict__ rowptr,
    const int* __restrict__ csrc, float* __restrict__ self)
{
    const int tx   = threadIdx.x;         // 0..23
    const int ty   = threadIdx.y;         // 0..7
    const int node = blockIdx.x * 8 + ty; // grid sized exactly: 6250*8 = 50000
    const int col  = tx * 4;

    const int r0 = rowptr[node];
    const int r1 = rowptr[node + 1];

    float4 a = *(const float4*)(self + (size_t)node * DIM + col);

    int j = r0;
    for (; j + 1 < r1; j += 2) {
        const int s0 = csrc[j];
        const int s1 = csrc[j + 1];
        const float4 v0 = *(const float4*)(t2 + (size_t)s0 * DIM + col);
        const float4 v1 = *(const float4*)(t2 + (size_t)s1 * DIM + col);
        a.x += v0.x; a.y += v0.y; a.z += v0.z; a.w += v0.w;
        a.x += v1.x; a.y += v1.y; a.z += v1.z; a.w += v1.w;
    }
    if (j < r1) {
        const int s0 = csrc[j];
        const float4 v0 = *(const float4*)(t2 + (size_t)s0 * DIM + col);
        a.x += v0.x; a.y += v0.y; a.z += v0.z; a.w += v0.w;
    }

    *(float4*)(self + (size_t)node * DIM + col) = a;
}

// ---------------------------------------------------------------------------
// Graph pooling: batch is sorted -> contiguous ranges; relu applied on read.
// ---------------------------------------------------------------------------
__global__ __launch_bounds__(384) void pool_graphs(
    const float* __restrict__ h, const int* __restrict__ batch,
    float* __restrict__ gemb)
{
    const int g = blockIdx.x;

    int lo = 0, hi = N_NODES;
    while (lo < hi) { int m = (lo + hi) >> 1; if (batch[m] < g) lo = m + 1; else hi = m; }
    const int start = lo;
    hi = N_NODES;
    while (lo < hi) { int m = (lo + hi) >> 1; if (batch[m] < g + 1) lo = m + 1; else hi = m; }
    const int end = lo;

    const int col = threadIdx.x;   // 0..95
    const int ty  = threadIdx.y;   // 0..3
    float s = 0.f;
    for (int n = start + ty; n < end; n += 4)
        s += fmaxf(h[(size_t)n * DIM + col], 0.f);

    __shared__ float part[4][DIM];
    part[ty][col] = s;
    __syncthreads();
    if (ty == 0)
        gemb[g * DIM + col] = part[0][col] + part[1][col] + part[2][col] + part[3][col];
}

// ---------------------------------------------------------------------------
// Classifier head.
// ---------------------------------------------------------------------------
__global__ __launch_bounds__(128) void classify(
    const float* __restrict__ gemb, const float* __restrict__ cw1,
    const float* __restrict__ cb1,  const float* __restrict__ cw2,
    const float* __restrict__ cb2,  float* __restrict__ out)
{
    const int g = blockIdx.x;
    const int t = threadIdx.x;

    __shared__ float gr[DIM];
    __shared__ float hid[DIM];

    if (t < DIM) gr[t] = gemb[g * DIM + t];
    __syncthreads();

    if (t < DIM) {
        float s = cb1[t];
#pragma unroll 4
        for (int k = 0; k < DIM; k++) s += gr[k] * cw1[k * DIM + t];
        hid[t] = fmaxf(s, 0.f);
    }
    __syncthreads();

    if (t < OUT_DIM) {
        float o = cb2[t];
#pragma unroll 4
        for (int k = 0; k < DIM; k++) o += hid[k] * cw2[k * OUT_DIM + t];
        out[g * OUT_DIM + t] = o;
    }
}

// ---------------------------------------------------------------------------
extern "C" void kernel_launch(void* const* d_in, const int* in_sizes, int n_in,
                              void* d_out, int out_size, void* d_ws, size_t ws_size,
                              hipStream_t stream)
{
    const float* x     = (const float*)d_in[0];
    const int*   ei    = (const int*)  d_in[1];
    const int*   batch = (const int*)  d_in[2];
    const float* W1    = (const float*)d_in[3];
    const float* W2    = (const float*)d_in[4];
    const float* cw1   = (const float*)d_in[5];
    const float* cb1   = (const float*)d_in[6];
    const float* cw2   = (const float*)d_in[7];
    const float* cb2   = (const float*)d_in[8];
    float*       out   = (float*)d_out;

    const int* src = ei;             // edge_index[0]
    const int* dst = ei + N_EDGES;   // edge_index[1]

    // workspace layout
    float* bufA = (float*)d_ws;                       // self/h ping
    float* bufB = bufA + (size_t)N_NODES * DIM;       // self/h pong
    float* bufT = bufB + (size_t)N_NODES * DIM;       // t2 scratch
    float* gemb = bufT + (size_t)N_NODES * DIM;       // [G, D]
    int*   deg    = (int*)(gemb + (size_t)N_GRAPHS * DIM);
    int*   rowptr = deg + N_NODES;                    // [N+1]
    int*   cursor = rowptr + (N_NODES + 1);           // [N]
    int*   csrc   = cursor + N_NODES;                 // [E]
    int*   bsum   = csrc + N_EDGES;                   // [SCAN_NB]

    // ---- CSR build (once per launch; reused by all 3 layers) ----
    zero_deg<<<(N_NODES + 255) / 256, 256, 0, stream>>>(deg);
    hist_dst<<<N_EDGES / 256, 256, 0, stream>>>(dst, deg);
    scan_phase_a<<<SCAN_NB, 256, 0, stream>>>(deg, bsum);
    scan_phase_b<<<1, 256, 0, stream>>>(bsum, rowptr);
    scan_phase_c<<<SCAN_NB, 256, 0, stream>>>(deg, bsum, rowptr, cursor);
    fill_csr<<<N_EDGES / 256, 256, 0, stream>>>(src, dst, cursor, csrc);

    const dim3 gblk(24, 8);
    const int  gGrid  = (N_NODES + 31) / 32;          // 1563
    const int  aGrid  = N_NODES / 8;                  // 6250 (exact)

    const float* hin  = x;      // pre-relu except layer 0 = x
    float*       selb = bufA;

    for (int l = 0; l < 3; l++) {
        const float* w1l = W1 + (size_t)l * DIM * DIM;
        const float* w2l = W2 + (size_t)l * DIM * DIM;
        if (l == 0)
            gemm_node<false><<<gGrid, gblk, 0, stream>>>(hin, w1l, w2l, selb, bufT);
        else
            gemm_node<true ><<<gGrid, gblk, 0, stream>>>(hin, w1l, w2l, selb, bufT);

        gather_nodes<<<aGrid, gblk, 0, stream>>>(bufT, rowptr, csrc, selb);

        hin  = selb;                       // pre-relu; consumers relu on read
        selb = (selb == bufA) ? bufB : bufA;
    }

    pool_graphs<<<N_GRAPHS, dim3(96, 4), 0, stream>>>(hin, batch, gemb);
    classify<<<N_GRAPHS, 128, 0, stream>>>(gemb, cw1, cb1, cw2, cb2, out);
}

// Round 4
// 387.297 us; speedup vs baseline: 8.6523x; 1.5241x over previous
//
#include <hip/hip_runtime.h>

#define N_NODES   50000
#define N_EDGES   800000
#define DIM       96
#define N_GRAPHS  128
#define OUT_DIM   10
#define SCAN_NB   ((N_NODES + 255) / 256)   // 196 blocks for the degree scan
#define ROWSTRIDE 192                        // bf16 elems per node row: [h(96) | n_agg(96)]
#define NPAD      50048                      // 782 * 64 rows (gemm grid coverage)

typedef __attribute__((ext_vector_type(8))) short          short8;
typedef __attribute__((ext_vector_type(8))) unsigned short u16x8;
typedef __attribute__((ext_vector_type(4))) float          f32x4;

__device__ __forceinline__ float b2f(unsigned short u) {
    union { unsigned int i; float f; } v; v.i = ((unsigned int)u) << 16; return v.f;
}
__device__ __forceinline__ unsigned short f2b(float f) {   // round-to-nearest-even
    union { float f; unsigned int i; } v; v.f = f;
    unsigned int u = v.i;
    return (unsigned short)((u + 0x7fffu + ((u >> 16) & 1u)) >> 16);
}

// ---------------------------------------------------------------------------
// x (fp32 [N,96]) -> bf16 into cols 0..95 of hbuf ([NPAD,192])
// ---------------------------------------------------------------------------
__global__ __launch_bounds__(256) void cast_x(const float* __restrict__ x,
                                              unsigned short* __restrict__ hbuf)
{
    const int tid = blockIdx.x * 256 + threadIdx.x;    // one per 8 cols
    if (tid >= N_NODES * 12) return;
    const int node = tid / 12;
    const int c    = (tid - node * 12) * 8;
    const float4 v0 = *(const float4*)(x + (size_t)node * DIM + c);
    const float4 v1 = *(const float4*)(x + (size_t)node * DIM + c + 4);
    u16x8 o;
    o[0] = f2b(v0.x); o[1] = f2b(v0.y); o[2] = f2b(v0.z); o[3] = f2b(v0.w);
    o[4] = f2b(v1.x); o[5] = f2b(v1.y); o[6] = f2b(v1.z); o[7] = f2b(v1.w);
    *(u16x8*)(hbuf + (size_t)node * ROWSTRIDE + c) = o;
}

// ---------------------------------------------------------------------------
// Build Bt[l][n][k] (bf16, k-major): k<96 -> W1[l][k][n], k>=96 -> W2[l][k-96][n]
// ---------------------------------------------------------------------------
__global__ __launch_bounds__(256) void conv_w(const float* __restrict__ W1,
                                              const float* __restrict__ W2,
                                              unsigned short* __restrict__ Bt)
{
    const int idx = blockIdx.x * 256 + threadIdx.x;
    if (idx >= 3 * DIM * ROWSTRIDE) return;
    const int l   = idx / (DIM * ROWSTRIDE);
    const int rem = idx - l * (DIM * ROWSTRIDE);
    const int n   = rem / ROWSTRIDE;
    const int k   = rem - n * ROWSTRIDE;
    const float v = (k < DIM) ? W1[(size_t)l * DIM * DIM + k * DIM + n]
                              : W2[(size_t)l * DIM * DIM + (k - DIM) * DIM + n];
    Bt[idx] = f2b(v);
}

// ---------------------------------------------------------------------------
// CSR build (by destination).
// ---------------------------------------------------------------------------
__global__ __launch_bounds__(256) void zero_deg(int* __restrict__ deg)
{
    const int i = blockIdx.x * 256 + threadIdx.x;
    if (i < N_NODES) deg[i] = 0;
}

__global__ __launch_bounds__(256) void hist_dst(const int* __restrict__ dst,
                                                int* __restrict__ deg)
{
    const int e = blockIdx.x * 256 + threadIdx.x;
    if (e < N_EDGES) atomicAdd(&deg[dst[e]], 1);
}

__global__ __launch_bounds__(256) void scan_phase_a(const int* __restrict__ deg,
                                                    int* __restrict__ bsum)
{
    const int i = blockIdx.x * 256 + threadIdx.x;
    int v = (i < N_NODES) ? deg[i] : 0;
#pragma unroll
    for (int off = 32; off > 0; off >>= 1) v += __shfl_down(v, off, 64);
    __shared__ int ws[4];
    if ((threadIdx.x & 63) == 0) ws[threadIdx.x >> 6] = v;
    __syncthreads();
    if (threadIdx.x == 0) bsum[blockIdx.x] = ws[0] + ws[1] + ws[2] + ws[3];
}

__global__ __launch_bounds__(256) void scan_phase_b(int* __restrict__ bsum,
                                                    int* __restrict__ rowptr)
{
    __shared__ int buf[2][256];
    const int t = threadIdx.x;
    int v = (t < SCAN_NB) ? bsum[t] : 0;
    buf[0][t] = v;
    __syncthreads();
    int cur = 0;
#pragma unroll
    for (int off = 1; off < 256; off <<= 1) {
        int x = buf[cur][t];
        if (t >= off) x += buf[cur][t - off];
        buf[cur ^ 1][t] = x;
        __syncthreads();
        cur ^= 1;
    }
    if (t < SCAN_NB) bsum[t] = (t == 0) ? 0 : buf[cur][t - 1];
    if (t == SCAN_NB - 1) rowptr[N_NODES] = buf[cur][SCAN_NB - 1];
}

__global__ __launch_bounds__(256) void scan_phase_c(const int* __restrict__ deg,
                                                    const int* __restrict__ bsum,
                                                    int* __restrict__ rowptr,
                                                    int* __restrict__ cursor)
{
    __shared__ int buf[2][256];
    const int i = blockIdx.x * 256 + threadIdx.x;
    const int t = threadIdx.x;
    int v = (i < N_NODES) ? deg[i] : 0;
    buf[0][t] = v;
    __syncthreads();
    int cur = 0;
#pragma unroll
    for (int off = 1; off < 256; off <<= 1) {
        int x = buf[cur][t];
        if (t >= off) x += buf[cur][t - off];
        buf[cur ^ 1][t] = x;
        __syncthreads();
        cur ^= 1;
    }
    if (i < N_NODES) {
        const int excl = bsum[blockIdx.x] + ((t == 0) ? 0 : buf[cur][t - 1]);
        rowptr[i] = excl;
        cursor[i] = excl;
    }
}

__global__ __launch_bounds__(256) void fill_csr(const int* __restrict__ src,
                                                const int* __restrict__ dst,
                                                int* __restrict__ cursor,
                                                int* __restrict__ csrc)
{
    const int e = blockIdx.x * 256 + threadIdx.x;
    if (e < N_EDGES) {
        const int pos = atomicAdd(&cursor[dst[e]], 1);
        csrc[pos] = src[e];
    }
}

// ---------------------------------------------------------------------------
// Pull aggregation of RAW h rows (linear trick: sum first, transform in gemm).
// Reads cols 0..95 (bf16), accumulates fp32, writes cols 96..191 of SAME buf.
// Block (12,16): 16 nodes/block, 12 threads x 16B per row.  Zero atomics.
// ---------------------------------------------------------------------------
__global__ __launch_bounds__(192) void gather_bf16(
    unsigned short* __restrict__ hbuf, const int* __restrict__ rowptr,
    const int* __restrict__ csrc)
{
    const int tx   = threadIdx.x;          // 0..11
    const int ty   = threadIdx.y;          // 0..15
    const int node = blockIdx.x * 16 + ty; // grid 3125 exact
    const int off  = tx * 8;               // 8 bf16 = 16B per thread

    const int r0 = rowptr[node];
    const int r1 = rowptr[node + 1];

    float a[8];
#pragma unroll
    for (int i = 0; i < 8; i++) a[i] = 0.f;

    int j = r0;
    for (; j + 1 < r1; j += 2) {
        const int s0 = csrc[j];
        const int s1 = csrc[j + 1];
        const u16x8 v0 = *(const u16x8*)(hbuf + (size_t)s0 * ROWSTRIDE + off);
        const u16x8 v1 = *(const u16x8*)(hbuf + (size_t)s1 * ROWSTRIDE + off);
#pragma unroll
        for (int i = 0; i < 8; i++) a[i] += b2f(v0[i]);
#pragma unroll
        for (int i = 0; i < 8; i++) a[i] += b2f(v1[i]);
    }
    if (j < r1) {
        const int s0 = csrc[j];
        const u16x8 v0 = *(const u16x8*)(hbuf + (size_t)s0 * ROWSTRIDE + off);
#pragma unroll
        for (int i = 0; i < 8; i++) a[i] += b2f(v0[i]);
    }

    u16x8 o;
#pragma unroll
    for (int i = 0; i < 8; i++) o[i] = f2b(a[i]);
    *(u16x8*)(hbuf + (size_t)node * ROWSTRIDE + DIM + off) = o;
}

// ---------------------------------------------------------------------------
// MFMA GEMM: Hout[:,0:96] = relu( A[N,192] @ B[192,96] ), bf16 in/out, fp32 acc.
// Block = 6 waves (384 thr); wave w owns col-tile 16w..16w+15; block covers 64
// rows (4 row-tiles of 16).  B staged per-wave in registers from Bt[n][k].
// mfma_f32_16x16x32_bf16: A-frag A[m=lane&15][k=quad*8+j]; C/D col=lane&15,
// row=quad*4+reg  (m89-verified layouts).
// ---------------------------------------------------------------------------
__global__ __launch_bounds__(384) void gemm_mfma(
    const unsigned short* __restrict__ A, const unsigned short* __restrict__ Bt,
    unsigned short* __restrict__ Hout)
{
    const int lane = threadIdx.x & 63;
    const int w    = threadIdx.x >> 6;   // 0..5 col tile
    const int m    = lane & 15;
    const int q    = lane >> 4;

    short8 bfrag[6];
#pragma unroll
    for (int s = 0; s < 6; s++)
        bfrag[s] = *(const short8*)(Bt + (size_t)(w * 16 + m) * ROWSTRIDE + s * 32 + q * 8);

    const int rowBase = blockIdx.x * 64;

#pragma unroll
    for (int r = 0; r < 4; r++) {
        const int rb = rowBase + r * 16;
        f32x4 acc = {0.f, 0.f, 0.f, 0.f};
        const unsigned short* arow = A + (size_t)(rb + m) * ROWSTRIDE + q * 8;
#pragma unroll
        for (int s = 0; s < 6; s++) {
            const short8 af = *(const short8*)(arow + s * 32);
            acc = __builtin_amdgcn_mfma_f32_16x16x32_bf16(af, bfrag[s], acc, 0, 0, 0);
        }
#pragma unroll
        for (int i = 0; i < 4; i++) {
            const int grow = rb + q * 4 + i;
            if (grow < N_NODES)
                Hout[(size_t)grow * ROWSTRIDE + w * 16 + m] = f2b(fmaxf(acc[i], 0.f));
        }
    }
}

// ---------------------------------------------------------------------------
// Graph pooling: h stored POST-relu bf16 in cols 0..95; batch sorted.
// ---------------------------------------------------------------------------
__global__ __launch_bounds__(384) void pool_graphs(
    const unsigned short* __restrict__ h, const int* __restrict__ batch,
    float* __restrict__ gemb)
{
    const int g = blockIdx.x;

    int lo = 0, hi = N_NODES;
    while (lo < hi) { int m = (lo + hi) >> 1; if (batch[m] < g) lo = m + 1; else hi = m; }
    const int start = lo;
    hi = N_NODES;
    while (lo < hi) { int m = (lo + hi) >> 1; if (batch[m] < g + 1) lo = m + 1; else hi = m; }
    const int end = lo;

    const int col = threadIdx.x;   // 0..95
    const int ty  = threadIdx.y;   // 0..3
    float s = 0.f;
    for (int n = start + ty; n < end; n += 4)
        s += b2f(h[(size_t)n * ROWSTRIDE + col]);

    __shared__ float part[4][DIM];
    part[ty][col] = s;
    __syncthreads();
    if (ty == 0)
        gemb[g * DIM + col] = part[0][col] + part[1][col] + part[2][col] + part[3][col];
}

// ---------------------------------------------------------------------------
// Classifier head (fp32).
// ---------------------------------------------------------------------------
__global__ __launch_bounds__(128) void classify(
    const float* __restrict__ gemb, const float* __restrict__ cw1,
    const float* __restrict__ cb1,  const float* __restrict__ cw2,
    const float* __restrict__ cb2,  float* __restrict__ out)
{
    const int g = blockIdx.x;
    const int t = threadIdx.x;

    __shared__ float gr[DIM];
    __shared__ float hid[DIM];

    if (t < DIM) gr[t] = gemb[g * DIM + t];
    __syncthreads();

    if (t < DIM) {
        float s = cb1[t];
#pragma unroll 4
        for (int k = 0; k < DIM; k++) s += gr[k] * cw1[k * DIM + t];
        hid[t] = fmaxf(s, 0.f);
    }
    __syncthreads();

    if (t < OUT_DIM) {
        float o = cb2[t];
#pragma unroll 4
        for (int k = 0; k < DIM; k++) o += hid[k] * cw2[k * OUT_DIM + t];
        out[g * OUT_DIM + t] = o;
    }
}

// ---------------------------------------------------------------------------
extern "C" void kernel_launch(void* const* d_in, const int* in_sizes, int n_in,
                              void* d_out, int out_size, void* d_ws, size_t ws_size,
                              hipStream_t stream)
{
    const float* x     = (const float*)d_in[0];
    const int*   ei    = (const int*)  d_in[1];
    const int*   batch = (const int*)  d_in[2];
    const float* W1    = (const float*)d_in[3];
    const float* W2    = (const float*)d_in[4];
    const float* cw1   = (const float*)d_in[5];
    const float* cb1   = (const float*)d_in[6];
    const float* cw2   = (const float*)d_in[7];
    const float* cb2   = (const float*)d_in[8];
    float*       out   = (float*)d_out;

    const int* src = ei;             // edge_index[0]
    const int* dst = ei + N_EDGES;   // edge_index[1]

    // workspace layout (bytes are 16B-aligned at each boundary)
    unsigned short* bufA = (unsigned short*)d_ws;            // [NPAD,192] bf16
    unsigned short* bufB = bufA + (size_t)NPAD * ROWSTRIDE;  // [NPAD,192] bf16
    unsigned short* Bt   = bufB + (size_t)NPAD * ROWSTRIDE;  // [3,96,192] bf16
    float* gemb   = (float*)(Bt + 3 * DIM * ROWSTRIDE);      // [G,D] fp32
    int*   deg    = (int*)(gemb + (size_t)N_GRAPHS * DIM);
    int*   rowptr = deg + N_NODES;                           // [N+1]
    int*   cursor = rowptr + (N_NODES + 1);                  // [N]
    int*   csrc   = cursor + N_NODES;                        // [E]
    int*   bsum   = csrc + N_EDGES;                          // [SCAN_NB]

    // ---- one-time converts + CSR build ----
    cast_x<<<(N_NODES * 12 + 255) / 256, 256, 0, stream>>>(x, bufA);
    conv_w<<<(3 * DIM * ROWSTRIDE + 255) / 256, 256, 0, stream>>>(W1, W2, Bt);
    zero_deg<<<(N_NODES + 255) / 256, 256, 0, stream>>>(deg);
    hist_dst<<<N_EDGES / 256, 256, 0, stream>>>(dst, deg);
    scan_phase_a<<<SCAN_NB, 256, 0, stream>>>(deg, bsum);
    scan_phase_b<<<1, 256, 0, stream>>>(bsum, rowptr);
    scan_phase_c<<<SCAN_NB, 256, 0, stream>>>(deg, bsum, rowptr, cursor);
    fill_csr<<<N_EDGES / 256, 256, 0, stream>>>(src, dst, cursor, csrc);

    unsigned short* hin  = bufA;
    unsigned short* hout = bufB;

    for (int l = 0; l < 3; l++) {
        gather_bf16<<<N_NODES / 16, dim3(12, 16), 0, stream>>>(hin, rowptr, csrc);
        gemm_mfma<<<NPAD / 64, 384, 0, stream>>>(hin, Bt + (size_t)l * DIM * ROWSTRIDE,
                                                 hout);
        unsigned short* t = hin; hin = hout; hout = t;
    }

    pool_graphs<<<N_GRAPHS, dim3(96, 4), 0, stream>>>(hin, batch, gemb);
    classify<<<N_GRAPHS, 128, 0, stream>>>(gemb, cw1, cb1, cw2, cb2, out);
}

// Round 5
// 338.995 us; speedup vs baseline: 9.8851x; 1.1425x over previous
//
#include <hip/hip_runtime.h>

#define N_NODES   50000
#define N_EDGES   800000
#define DIM       96
#define N_GRAPHS  128
#define OUT_DIM   10
#define ROWSTRIDE 192          // bf16 elems per node row: [h(96) | n_agg(96)]
#define NPAD      50048        // 782 * 64 rows (gemm grid coverage)
#define CAP       64           // bucket capacity (max in-degree; Poisson(16) tail ~1e-20)

typedef __attribute__((ext_vector_type(8))) short          short8;
typedef __attribute__((ext_vector_type(8))) unsigned short u16x8;
typedef __attribute__((ext_vector_type(4))) float          f32x4;

__device__ __forceinline__ float b2f(unsigned short u) {
    union { unsigned int i; float f; } v; v.i = ((unsigned int)u) << 16; return v.f;
}
__device__ __forceinline__ unsigned short f2b(float f) {   // round-to-nearest-even
    union { float f; unsigned int i; } v; v.f = f;
    unsigned int u = v.i;
    return (unsigned short)((u + 0x7fffu + ((u >> 16) & 1u)) >> 16);
}

// ---------------------------------------------------------------------------
// x (fp32 [N,96]) -> bf16 into cols 0..95 of hbuf ([NPAD,192])
// ---------------------------------------------------------------------------
__global__ __launch_bounds__(256) void cast_x(const float* __restrict__ x,
                                              unsigned short* __restrict__ hbuf)
{
    const int tid = blockIdx.x * 256 + threadIdx.x;    // one per 8 cols
    if (tid >= N_NODES * 12) return;
    const int node = tid / 12;
    const int c    = (tid - node * 12) * 8;
    const float4 v0 = *(const float4*)(x + (size_t)node * DIM + c);
    const float4 v1 = *(const float4*)(x + (size_t)node * DIM + c + 4);
    u16x8 o;
    o[0] = f2b(v0.x); o[1] = f2b(v0.y); o[2] = f2b(v0.z); o[3] = f2b(v0.w);
    o[4] = f2b(v1.x); o[5] = f2b(v1.y); o[6] = f2b(v1.z); o[7] = f2b(v1.w);
    *(u16x8*)(hbuf + (size_t)node * ROWSTRIDE + c) = o;
}

// ---------------------------------------------------------------------------
// Build Bt[l][n][k] (bf16, k-major): k<96 -> W1[l][k][n], k>=96 -> W2[l][k-96][n]
// ---------------------------------------------------------------------------
__global__ __launch_bounds__(256) void conv_w(const float* __restrict__ W1,
                                              const float* __restrict__ W2,
                                              unsigned short* __restrict__ Bt)
{
    const int idx = blockIdx.x * 256 + threadIdx.x;
    if (idx >= 3 * DIM * ROWSTRIDE) return;
    const int l   = idx / (DIM * ROWSTRIDE);
    const int rem = idx - l * (DIM * ROWSTRIDE);
    const int n   = rem / ROWSTRIDE;
    const int k   = rem - n * ROWSTRIDE;
    const float v = (k < DIM) ? W1[(size_t)l * DIM * DIM + k * DIM + n]
                              : W2[(size_t)l * DIM * DIM + (k - DIM) * DIM + n];
    Bt[idx] = f2b(v);
}

// ---------------------------------------------------------------------------
// Bucketed CSR: cursor padded to one counter per 64B line (kills line-level
// atomic serialization); csrc[node*CAP + pos].  No histogram, no scan.
// ---------------------------------------------------------------------------
__global__ __launch_bounds__(256) void zero_cursor(int* __restrict__ cursor)
{
    const int i = blockIdx.x * 256 + threadIdx.x;
    if (i < N_NODES * 16) cursor[i] = 0;
}

__global__ __launch_bounds__(256) void fill_bucket(const int* __restrict__ src,
                                                   const int* __restrict__ dst,
                                                   int* __restrict__ cursor,
                                                   int* __restrict__ csrc)
{
    const int e = blockIdx.x * 256 + threadIdx.x;
    if (e >= N_EDGES) return;
    const int d   = dst[e];
    const int pos = atomicAdd(&cursor[d << 4], 1);
    if (pos < CAP) csrc[d * CAP + pos] = src[e];
}

// ---------------------------------------------------------------------------
// Pull aggregation of RAW h rows (linear trick: sum first, transform in gemm).
// Reads cols 0..95 (bf16), accumulates fp32, writes cols 96..191 of SAME buf.
// Block (12,16): 16 nodes/block, 12 threads x 16B per row.  Bucket base is
// 256B-aligned -> aligned int4 src reads; 4 independent row loads in flight.
// ---------------------------------------------------------------------------
__global__ __launch_bounds__(192) void gather_bucket(
    unsigned short* __restrict__ hbuf, const int* __restrict__ cursor,
    const int* __restrict__ csrc)
{
    const int tx   = threadIdx.x;          // 0..11
    const int ty   = threadIdx.y;          // 0..15
    const int node = blockIdx.x * 16 + ty; // grid 3125 exact
    const int off  = tx * 8;               // 8 bf16 = 16B per thread

    const int deg = min(cursor[node << 4], CAP);
    const int* __restrict__ bkt = csrc + node * CAP;
    const unsigned short* __restrict__ hb = hbuf + off;

    float a[8];
#pragma unroll
    for (int i = 0; i < 8; i++) a[i] = 0.f;

    const int nfull = deg & ~3;
    int c = 0;
    for (; c < nfull; c += 4) {
        const int4 s = *(const int4*)(bkt + c);
        const u16x8 v0 = *(const u16x8*)(hb + (size_t)s.x * ROWSTRIDE);
        const u16x8 v1 = *(const u16x8*)(hb + (size_t)s.y * ROWSTRIDE);
        const u16x8 v2 = *(const u16x8*)(hb + (size_t)s.z * ROWSTRIDE);
        const u16x8 v3 = *(const u16x8*)(hb + (size_t)s.w * ROWSTRIDE);
#pragma unroll
        for (int i = 0; i < 8; i++) a[i] += b2f(v0[i]);
#pragma unroll
        for (int i = 0; i < 8; i++) a[i] += b2f(v1[i]);
#pragma unroll
        for (int i = 0; i < 8; i++) a[i] += b2f(v2[i]);
#pragma unroll
        for (int i = 0; i < 8; i++) a[i] += b2f(v3[i]);
    }
    for (; c < deg; c++) {
        const int s0 = bkt[c];
        const u16x8 v0 = *(const u16x8*)(hb + (size_t)s0 * ROWSTRIDE);
#pragma unroll
        for (int i = 0; i < 8; i++) a[i] += b2f(v0[i]);
    }

    u16x8 o;
#pragma unroll
    for (int i = 0; i < 8; i++) o[i] = f2b(a[i]);
    *(u16x8*)(hbuf + (size_t)node * ROWSTRIDE + DIM + off) = o;
}

// ---------------------------------------------------------------------------
// MFMA GEMM: Hout[:,0:96] = relu( A[N,192] @ B[192,96] ), bf16 in/out, fp32 acc.
// Block = 6 waves (384 thr); wave w owns col-tile 16w..16w+15; block covers 64
// rows.  mfma_f32_16x16x32_bf16: A-frag A[m=lane&15][k=quad*8+j]; C/D
// col=lane&15, row=quad*4+reg  (m89-verified layouts).
// ---------------------------------------------------------------------------
__global__ __launch_bounds__(384) void gemm_mfma(
    const unsigned short* __restrict__ A, const unsigned short* __restrict__ Bt,
    unsigned short* __restrict__ Hout)
{
    const int lane = threadIdx.x & 63;
    const int w    = threadIdx.x >> 6;   // 0..5 col tile
    const int m    = lane & 15;
    const int q    = lane >> 4;

    short8 bfrag[6];
#pragma unroll
    for (int s = 0; s < 6; s++)
        bfrag[s] = *(const short8*)(Bt + (size_t)(w * 16 + m) * ROWSTRIDE + s * 32 + q * 8);

    const int rowBase = blockIdx.x * 64;

#pragma unroll
    for (int r = 0; r < 4; r++) {
        const int rb = rowBase + r * 16;
        f32x4 acc = {0.f, 0.f, 0.f, 0.f};
        const unsigned short* arow = A + (size_t)(rb + m) * ROWSTRIDE + q * 8;
#pragma unroll
        for (int s = 0; s < 6; s++) {
            const short8 af = *(const short8*)(arow + s * 32);
            acc = __builtin_amdgcn_mfma_f32_16x16x32_bf16(af, bfrag[s], acc, 0, 0, 0);
        }
#pragma unroll
        for (int i = 0; i < 4; i++) {
            const int grow = rb + q * 4 + i;
            if (grow < N_NODES)
                Hout[(size_t)grow * ROWSTRIDE + w * 16 + m] = f2b(fmaxf(acc[i], 0.f));
        }
    }
}

// ---------------------------------------------------------------------------
// Graph pooling: h stored POST-relu bf16 in cols 0..95; batch sorted.
// ---------------------------------------------------------------------------
__global__ __launch_bounds__(384) void pool_graphs(
    const unsigned short* __restrict__ h, const int* __restrict__ batch,
    float* __restrict__ gemb)
{
    const int g = blockIdx.x;

    int lo = 0, hi = N_NODES;
    while (lo < hi) { int m = (lo + hi) >> 1; if (batch[m] < g) lo = m + 1; else hi = m; }
    const int start = lo;
    hi = N_NODES;
    while (lo < hi) { int m = (lo + hi) >> 1; if (batch[m] < g + 1) lo = m + 1; else hi = m; }
    const int end = lo;

    const int col = threadIdx.x;   // 0..95
    const int ty  = threadIdx.y;   // 0..3
    float s = 0.f;
    for (int n = start + ty; n < end; n += 4)
        s += b2f(h[(size_t)n * ROWSTRIDE + col]);

    __shared__ float part[4][DIM];
    part[ty][col] = s;
    __syncthreads();
    if (ty == 0)
        gemb[g * DIM + col] = part[0][col] + part[1][col] + part[2][col] + part[3][col];
}

// ---------------------------------------------------------------------------
// Classifier head (fp32).
// ---------------------------------------------------------------------------
__global__ __launch_bounds__(128) void classify(
    const float* __restrict__ gemb, const float* __restrict__ cw1,
    const float* __restrict__ cb1,  const float* __restrict__ cw2,
    const float* __restrict__ cb2,  float* __restrict__ out)
{
    const int g = blockIdx.x;
    const int t = threadIdx.x;

    __shared__ float gr[DIM];
    __shared__ float hid[DIM];

    if (t < DIM) gr[t] = gemb[g * DIM + t];
    __syncthreads();

    if (t < DIM) {
        float s = cb1[t];
#pragma unroll 4
        for (int k = 0; k < DIM; k++) s += gr[k] * cw1[k * DIM + t];
        hid[t] = fmaxf(s, 0.f);
    }
    __syncthreads();

    if (t < OUT_DIM) {
        float o = cb2[t];
#pragma unroll 4
        for (int k = 0; k < DIM; k++) o += hid[k] * cw2[k * OUT_DIM + t];
        out[g * OUT_DIM + t] = o;
    }
}

// ---------------------------------------------------------------------------
extern "C" void kernel_launch(void* const* d_in, const int* in_sizes, int n_in,
                              void* d_out, int out_size, void* d_ws, size_t ws_size,
                              hipStream_t stream)
{
    const float* x     = (const float*)d_in[0];
    const int*   ei    = (const int*)  d_in[1];
    const int*   batch = (const int*)  d_in[2];
    const float* W1    = (const float*)d_in[3];
    const float* W2    = (const float*)d_in[4];
    const float* cw1   = (const float*)d_in[5];
    const float* cb1   = (const float*)d_in[6];
    const float* cw2   = (const float*)d_in[7];
    const float* cb2   = (const float*)d_in[8];
    float*       out   = (float*)d_out;

    const int* src = ei;             // edge_index[0]
    const int* dst = ei + N_EDGES;   // edge_index[1]

    // workspace layout (16B-aligned at each boundary)
    unsigned short* bufA = (unsigned short*)d_ws;            // [NPAD,192] bf16
    unsigned short* bufB = bufA + (size_t)NPAD * ROWSTRIDE;  // [NPAD,192] bf16
    unsigned short* Bt   = bufB + (size_t)NPAD * ROWSTRIDE;  // [3,96,192] bf16
    float* gemb   = (float*)(Bt + 3 * DIM * ROWSTRIDE);      // [G,D] fp32
    int*   cursor = (int*)(gemb + (size_t)N_GRAPHS * DIM);   // [N*16] line-padded
    int*   csrc   = cursor + (size_t)N_NODES * 16;           // [N*CAP]

    // ---- one-time converts + bucketed CSR build ----
    cast_x<<<(N_NODES * 12 + 255) / 256, 256, 0, stream>>>(x, bufA);
    conv_w<<<(3 * DIM * ROWSTRIDE + 255) / 256, 256, 0, stream>>>(W1, W2, Bt);
    zero_cursor<<<(N_NODES * 16 + 255) / 256, 256, 0, stream>>>(cursor);
    fill_bucket<<<N_EDGES / 256, 256, 0, stream>>>(src, dst, cursor, csrc);

    unsigned short* hin  = bufA;
    unsigned short* hout = bufB;

    for (int l = 0; l < 3; l++) {
        gather_bucket<<<N_NODES / 16, dim3(12, 16), 0, stream>>>(hin, cursor, csrc);
        gemm_mfma<<<NPAD / 64, 384, 0, stream>>>(hin, Bt + (size_t)l * DIM * ROWSTRIDE,
                                                 hout);
        unsigned short* t = hin; hin = hout; hout = t;
    }

    pool_graphs<<<N_GRAPHS, dim3(96, 4), 0, stream>>>(hin, batch, gemb);
    classify<<<N_GRAPHS, 128, 0, stream>>>(gemb, cw1, cb1, cw2, cb2, out);
}

// Round 6
// 297.250 us; speedup vs baseline: 11.2733x; 1.1404x over previous
//
#include <hip/hip_runtime.h>

#define N_NODES   50000
#define N_EDGES   800000
#define DIM       96
#define N_GRAPHS  128
#define OUT_DIM   10
#define NPAD      50048        // 782 * 64 rows (gemm grid coverage)
#define CAP       64           // per-node bucket capacity (Poisson(16) tail ~1e-20)
#define NBINS     391          // coarse bins of 128 nodes: (50000+127)/128
#define BINCAP    4096         // edges per coarse bin (Poisson(2048), sd~45)
#define P1_BLOCKS 128
#define EPB       (N_EDGES / P1_BLOCKS)   // 6250

typedef __attribute__((ext_vector_type(8))) short          short8;
typedef __attribute__((ext_vector_type(8))) unsigned short u16x8;
typedef __attribute__((ext_vector_type(4))) float          f32x4;

__device__ __forceinline__ float b2f(unsigned short u) {
    union { unsigned int i; float f; } v; v.i = ((unsigned int)u) << 16; return v.f;
}
__device__ __forceinline__ unsigned short f2b(float f) {   // round-to-nearest-even
    union { float f; unsigned int i; } v; v.f = f;
    unsigned int u = v.i;
    return (unsigned short)((u + 0x7fffu + ((u >> 16) & 1u)) >> 16);
}

// ---------------------------------------------------------------------------
// x (fp32 [N,96]) -> bf16 harr [NPAD,96] (compact, stride 96)
// ---------------------------------------------------------------------------
__global__ __launch_bounds__(256) void cast_x(const float* __restrict__ x,
                                              unsigned short* __restrict__ harr)
{
    const int tid = blockIdx.x * 256 + threadIdx.x;    // one per 8 cols
    if (tid >= N_NODES * 12) return;
    const int node = tid / 12;
    const int c    = (tid - node * 12) * 8;
    const float4 v0 = *(const float4*)(x + (size_t)node * DIM + c);
    const float4 v1 = *(const float4*)(x + (size_t)node * DIM + c + 4);
    u16x8 o;
    o[0] = f2b(v0.x); o[1] = f2b(v0.y); o[2] = f2b(v0.z); o[3] = f2b(v0.w);
    o[4] = f2b(v1.x); o[5] = f2b(v1.y); o[6] = f2b(v1.z); o[7] = f2b(v1.w);
    *(u16x8*)(harr + (size_t)node * DIM + c) = o;
}

// ---------------------------------------------------------------------------
// Build Bt[l][n][k] (bf16, k-major): k<96 -> W1[l][k][n], k>=96 -> W2[l][k-96][n]
// ---------------------------------------------------------------------------
__global__ __launch_bounds__(256) void conv_w(const float* __restrict__ W1,
                                              const float* __restrict__ W2,
                                              unsigned short* __restrict__ Bt)
{
    const int idx = blockIdx.x * 256 + threadIdx.x;
    if (idx >= 3 * DIM * 2 * DIM) return;
    const int l   = idx / (DIM * 2 * DIM);
    const int rem = idx - l * (DIM * 2 * DIM);
    const int n   = rem / (2 * DIM);
    const int k   = rem - n * (2 * DIM);
    const float v = (k < DIM) ? W1[(size_t)l * DIM * DIM + k * DIM + n]
                              : W2[(size_t)l * DIM * DIM + (k - DIM) * DIM + n];
    Bt[idx] = f2b(v);
}

// ---------------------------------------------------------------------------
// Two-pass binned CSR build.  Replaces 800k returning device atomics (round-5
// evidence: capped at ~1.1 TB/s of 64B-line traffic ~= 16G atomics/s) with
// ~50k global atomics + LDS-local contention.
// ---------------------------------------------------------------------------
__global__ __launch_bounds__(256) void zero_gcur(int* __restrict__ gcur)
{
    const int i = blockIdx.x * 256 + threadIdx.x;
    if (i < NBINS * 16) gcur[i] = 0;
}

// Pass 1: coarse-bin edges by dst>>7, packing (dstLow<<16)|src.
__global__ __launch_bounds__(256) void pass1_bin(const int* __restrict__ src,
                                                 const int* __restrict__ dst,
                                                 int* __restrict__ gcur,
                                                 int* __restrict__ binned)
{
    __shared__ int hist[NBINS];
    __shared__ int base[NBINS];
    const int t  = threadIdx.x;
    const int e0 = blockIdx.x * EPB;

    for (int b = t; b < NBINS; b += 256) hist[b] = 0;
    __syncthreads();

    for (int e = e0 + t; e < e0 + EPB; e += 256)
        atomicAdd(&hist[dst[e] >> 7], 1);
    __syncthreads();

    for (int b = t; b < NBINS; b += 256) {
        const int c = hist[b];
        base[b] = (c > 0) ? atomicAdd(&gcur[b << 4], c) : 0;
        hist[b] = 0;                       // reuse as local cursor
    }
    __syncthreads();

    for (int e = e0 + t; e < e0 + EPB; e += 256) {
        const int d   = dst[e];
        const int bin = d >> 7;
        const int pos = base[bin] + atomicAdd(&hist[bin], 1);
        if (pos < BINCAP)
            binned[bin * BINCAP + pos] = ((d & 127) << 16) | src[e];
    }
}

// Pass 2: one block per bin (128 nodes); LDS cursors claim per-node slots.
__global__ __launch_bounds__(256) void pass2_scatter(const int* __restrict__ gcur,
                                                     const int* __restrict__ binned,
                                                     int* __restrict__ csrc,
                                                     int* __restrict__ deg)
{
    __shared__ int ncnt[128];
    const int bin = blockIdx.x;
    const int t   = threadIdx.x;
    const int n0  = bin << 7;
    const int cnt = min(gcur[bin << 4], BINCAP);

    if (t < 128) ncnt[t] = 0;
    __syncthreads();

    const int* __restrict__ bb = binned + bin * BINCAP;
    for (int i = t; i < cnt; i += 256) {
        const int v    = bb[i];
        const int dlow = v >> 16;
        const int s    = v & 0xffff;
        const int pos  = atomicAdd(&ncnt[dlow], 1);
        if (pos < CAP) csrc[(size_t)(n0 + dlow) * CAP + pos] = s;
    }
    __syncthreads();

    if (t < 128 && n0 + t < N_NODES) deg[n0 + t] = min(ncnt[t], CAP);
}

// ---------------------------------------------------------------------------
// Pull aggregation of raw h rows: agg[n] = sum_{s in bucket(n)} harr[s].
// Block (12,16): 16 nodes/block, 12 threads x 16B per row; unroll 8 for MLP.
// ---------------------------------------------------------------------------
__global__ __launch_bounds__(192) void gather_bucket(
    const unsigned short* __restrict__ harr, const int* __restrict__ deg,
    const int* __restrict__ csrc, unsigned short* __restrict__ agg)
{
    const int tx   = threadIdx.x;          // 0..11
    const int ty   = threadIdx.y;          // 0..15
    const int node = blockIdx.x * 16 + ty; // grid 3125 exact
    const int off  = tx * 8;               // 8 bf16 = 16B per thread

    const int d = deg[node];
    const int* __restrict__ bkt = csrc + (size_t)node * CAP;
    const unsigned short* __restrict__ hb = harr + off;

    float a[8];
#pragma unroll
    for (int i = 0; i < 8; i++) a[i] = 0.f;

    const int nfull = d & ~7;
    int c = 0;
    for (; c < nfull; c += 8) {
        const int4 s0 = *(const int4*)(bkt + c);
        const int4 s1 = *(const int4*)(bkt + c + 4);
        u16x8 v[8];
        v[0] = *(const u16x8*)(hb + (size_t)s0.x * DIM);
        v[1] = *(const u16x8*)(hb + (size_t)s0.y * DIM);
        v[2] = *(const u16x8*)(hb + (size_t)s0.z * DIM);
        v[3] = *(const u16x8*)(hb + (size_t)s0.w * DIM);
        v[4] = *(const u16x8*)(hb + (size_t)s1.x * DIM);
        v[5] = *(const u16x8*)(hb + (size_t)s1.y * DIM);
        v[6] = *(const u16x8*)(hb + (size_t)s1.z * DIM);
        v[7] = *(const u16x8*)(hb + (size_t)s1.w * DIM);
#pragma unroll
        for (int r = 0; r < 8; r++)
#pragma unroll
            for (int i = 0; i < 8; i++) a[i] += b2f(v[r][i]);
    }
    for (; c < d; c++) {
        const int s0 = bkt[c];
        const u16x8 v0 = *(const u16x8*)(hb + (size_t)s0 * DIM);
#pragma unroll
        for (int i = 0; i < 8; i++) a[i] += b2f(v0[i]);
    }

    u16x8 o;
#pragma unroll
    for (int i = 0; i < 8; i++) o[i] = f2b(a[i]);
    *(u16x8*)(agg + (size_t)node * DIM + off) = o;
}

// ---------------------------------------------------------------------------
// MFMA GEMM: Hout = relu( [harr | agg] @ B[192,96] ), bf16 in/out, fp32 acc.
// K-chunks s=0..2 read harr, s=3..5 read agg (matches Bt k-order).
// mfma_f32_16x16x32_bf16: A-frag A[m=lane&15][k=quad*8+j]; C/D col=lane&15,
// row=quad*4+reg  (m89-verified layouts).
// ---------------------------------------------------------------------------
__global__ __launch_bounds__(384) void gemm_mfma(
    const unsigned short* __restrict__ A_h, const unsigned short* __restrict__ A_g,
    const unsigned short* __restrict__ Bt, unsigned short* __restrict__ Hout)
{
    const int lane = threadIdx.x & 63;
    const int w    = threadIdx.x >> 6;   // 0..5 col tile
    const int m    = lane & 15;
    const int q    = lane >> 4;

    short8 bfrag[6];
#pragma unroll
    for (int s = 0; s < 6; s++)
        bfrag[s] = *(const short8*)(Bt + (size_t)(w * 16 + m) * (2 * DIM) + s * 32 + q * 8);

    const int rowBase = blockIdx.x * 64;

#pragma unroll
    for (int r = 0; r < 4; r++) {
        const int rb = rowBase + r * 16;
        f32x4 acc = {0.f, 0.f, 0.f, 0.f};
        const unsigned short* ah = A_h + (size_t)(rb + m) * DIM + q * 8;
        const unsigned short* ag = A_g + (size_t)(rb + m) * DIM + q * 8;
#pragma unroll
        for (int s = 0; s < 3; s++) {
            const short8 af = *(const short8*)(ah + s * 32);
            acc = __builtin_amdgcn_mfma_f32_16x16x32_bf16(af, bfrag[s], acc, 0, 0, 0);
        }
#pragma unroll
        for (int s = 0; s < 3; s++) {
            const short8 af = *(const short8*)(ag + s * 32);
            acc = __builtin_amdgcn_mfma_f32_16x16x32_bf16(af, bfrag[s + 3], acc, 0, 0, 0);
        }
#pragma unroll
        for (int i = 0; i < 4; i++) {
            const int grow = rb + q * 4 + i;
            if (grow < N_NODES)
                Hout[(size_t)grow * DIM + w * 16 + m] = f2b(fmaxf(acc[i], 0.f));
        }
    }
}

// ---------------------------------------------------------------------------
// Graph pooling: h stored POST-relu bf16 (compact); batch sorted.
// ---------------------------------------------------------------------------
__global__ __launch_bounds__(384) void pool_graphs(
    const unsigned short* __restrict__ h, const int* __restrict__ batch,
    float* __restrict__ gemb)
{
    const int g = blockIdx.x;

    int lo = 0, hi = N_NODES;
    while (lo < hi) { int m = (lo + hi) >> 1; if (batch[m] < g) lo = m + 1; else hi = m; }
    const int start = lo;
    hi = N_NODES;
    while (lo < hi) { int m = (lo + hi) >> 1; if (batch[m] < g + 1) lo = m + 1; else hi = m; }
    const int end = lo;

    const int col = threadIdx.x;   // 0..95
    const int ty  = threadIdx.y;   // 0..3
    float s = 0.f;
    for (int n = start + ty; n < end; n += 4)
        s += b2f(h[(size_t)n * DIM + col]);

    __shared__ float part[4][DIM];
    part[ty][col] = s;
    __syncthreads();
    if (ty == 0)
        gemb[g * DIM + col] = part[0][col] + part[1][col] + part[2][col] + part[3][col];
}

// ---------------------------------------------------------------------------
// Classifier head (fp32).
// ---------------------------------------------------------------------------
__global__ __launch_bounds__(128) void classify(
    const float* __restrict__ gemb, const float* __restrict__ cw1,
    const float* __restrict__ cb1,  const float* __restrict__ cw2,
    const float* __restrict__ cb2,  float* __restrict__ out)
{
    const int g = blockIdx.x;
    const int t = threadIdx.x;

    __shared__ float gr[DIM];
    __shared__ float hid[DIM];

    if (t < DIM) gr[t] = gemb[g * DIM + t];
    __syncthreads();

    if (t < DIM) {
        float s = cb1[t];
#pragma unroll 4
        for (int k = 0; k < DIM; k++) s += gr[k] * cw1[k * DIM + t];
        hid[t] = fmaxf(s, 0.f);
    }
    __syncthreads();

    if (t < OUT_DIM) {
        float o = cb2[t];
#pragma unroll 4
        for (int k = 0; k < DIM; k++) o += hid[k] * cw2[k * OUT_DIM + t];
        out[g * OUT_DIM + t] = o;
    }
}

// ---------------------------------------------------------------------------
extern "C" void kernel_launch(void* const* d_in, const int* in_sizes, int n_in,
                              void* d_out, int out_size, void* d_ws, size_t ws_size,
                              hipStream_t stream)
{
    const float* x     = (const float*)d_in[0];
    const int*   ei    = (const int*)  d_in[1];
    const int*   batch = (const int*)  d_in[2];
    const float* W1    = (const float*)d_in[3];
    const float* W2    = (const float*)d_in[4];
    const float* cw1   = (const float*)d_in[5];
    const float* cb1   = (const float*)d_in[6];
    const float* cw2   = (const float*)d_in[7];
    const float* cb2   = (const float*)d_in[8];
    float*       out   = (float*)d_out;

    const int* src = ei;             // edge_index[0]
    const int* dst = ei + N_EDGES;   // edge_index[1]

    // workspace layout (16B-aligned at each boundary)
    unsigned short* bufA = (unsigned short*)d_ws;          // [NPAD,96] bf16
    unsigned short* bufB = bufA + (size_t)NPAD * DIM;      // [NPAD,96] bf16
    unsigned short* agg  = bufB + (size_t)NPAD * DIM;      // [NPAD,96] bf16
    unsigned short* Bt   = agg  + (size_t)NPAD * DIM;      // [3,96,192] bf16
    float* gemb   = (float*)(Bt + 3 * DIM * 2 * DIM);      // [G,D] fp32
    int*   gcur   = (int*)(gemb + (size_t)N_GRAPHS * DIM); // [NBINS*16] line-padded
    int*   binned = gcur + NBINS * 16;                     // [NBINS*BINCAP]
    int*   csrc   = binned + (size_t)NBINS * BINCAP;       // [N*CAP]
    int*   deg    = csrc + (size_t)N_NODES * CAP;          // [N]

    // ---- one-time converts + two-pass binned CSR build ----
    cast_x<<<(N_NODES * 12 + 255) / 256, 256, 0, stream>>>(x, bufA);
    conv_w<<<(3 * DIM * 2 * DIM + 255) / 256, 256, 0, stream>>>(W1, W2, Bt);
    zero_gcur<<<(NBINS * 16 + 255) / 256, 256, 0, stream>>>(gcur);
    pass1_bin<<<P1_BLOCKS, 256, 0, stream>>>(src, dst, gcur, binned);
    pass2_scatter<<<NBINS, 256, 0, stream>>>(gcur, binned, csrc, deg);

    unsigned short* hin  = bufA;
    unsigned short* hout = bufB;

    for (int l = 0; l < 3; l++) {
        gather_bucket<<<N_NODES / 16, dim3(12, 16), 0, stream>>>(hin, deg, csrc, agg);
        gemm_mfma<<<NPAD / 64, 384, 0, stream>>>(hin, agg,
                                                 Bt + (size_t)l * DIM * 2 * DIM, hout);
        unsigned short* t = hin; hin = hout; hout = t;
    }

    pool_graphs<<<N_GRAPHS, dim3(96, 4), 0, stream>>>(hin, batch, gemb);
    classify<<<N_GRAPHS, 128, 0, stream>>>(gemb, cw1, cb1, cw2, cb2, out);
}

// Round 7
// 267.664 us; speedup vs baseline: 12.5194x; 1.1105x over previous
//
#include <hip/hip_runtime.h>

#define N_NODES   50000
#define N_EDGES   800000
#define DIM       96
#define N_GRAPHS  128
#define OUT_DIM   10
#define NPAD      50048        // 782 * 64 rows (gemm grid coverage)
#define CAP       64           // per-node bucket capacity (Poisson(16) tail ~1e-20)
#define NBINS     391          // coarse bins of 128 nodes
#define BINCAP    4096         // edges per coarse bin (Poisson(2048))
#define P1_BLOCKS 256
#define EPB       (N_EDGES / P1_BLOCKS)   // 3125
#define LPAD      104          // LDS agg row stride (bank-spread for b128 reads)

#define CAST_NB   ((N_NODES * 12 + 255) / 256)        // 2344
#define CONV_NB   ((3 * DIM * 2 * DIM + 255) / 256)   // 216
#define ZERO_NB   ((NBINS * 16 + 255) / 256)          // 25

typedef __attribute__((ext_vector_type(8))) short          short8;
typedef __attribute__((ext_vector_type(8))) unsigned short u16x8;
typedef __attribute__((ext_vector_type(4))) float          f32x4;

__device__ __forceinline__ float b2f(unsigned short u) {
    union { unsigned int i; float f; } v; v.i = ((unsigned int)u) << 16; return v.f;
}
__device__ __forceinline__ unsigned short f2b(float f) {   // round-to-nearest-even
    union { float f; unsigned int i; } v; v.f = f;
    unsigned int u = v.i;
    return (unsigned short)((u + 0x7fffu + ((u >> 16) & 1u)) >> 16);
}

// ---------------------------------------------------------------------------
// prep: grid-partitioned fusion of {cast x -> bf16, build Bt, zero gcur}.
// ---------------------------------------------------------------------------
__global__ __launch_bounds__(256) void prep(const float* __restrict__ x,
                                            const float* __restrict__ W1,
                                            const float* __restrict__ W2,
                                            unsigned short* __restrict__ harr,
                                            unsigned short* __restrict__ Bt,
                                            int* __restrict__ gcur)
{
    const int b = blockIdx.x;
    const int t = threadIdx.x;
    if (b < CAST_NB) {
        const int tid = b * 256 + t;                  // one per 8 cols
        if (tid >= N_NODES * 12) return;
        const int node = tid / 12;
        const int c    = (tid - node * 12) * 8;
        const float4 v0 = *(const float4*)(x + (size_t)node * DIM + c);
        const float4 v1 = *(const float4*)(x + (size_t)node * DIM + c + 4);
        u16x8 o;
        o[0] = f2b(v0.x); o[1] = f2b(v0.y); o[2] = f2b(v0.z); o[3] = f2b(v0.w);
        o[4] = f2b(v1.x); o[5] = f2b(v1.y); o[6] = f2b(v1.z); o[7] = f2b(v1.w);
        *(u16x8*)(harr + (size_t)node * DIM + c) = o;
    } else if (b < CAST_NB + CONV_NB) {
        const int idx = (b - CAST_NB) * 256 + t;      // Bt[l][n][k], k-major
        if (idx >= 3 * DIM * 2 * DIM) return;
        const int l   = idx / (DIM * 2 * DIM);
        const int rem = idx - l * (DIM * 2 * DIM);
        const int n   = rem / (2 * DIM);
        const int k   = rem - n * (2 * DIM);
        const float v = (k < DIM) ? W1[(size_t)l * DIM * DIM + k * DIM + n]
                                  : W2[(size_t)l * DIM * DIM + (k - DIM) * DIM + n];
        Bt[idx] = f2b(v);
    } else {
        const int i = (b - CAST_NB - CONV_NB) * 256 + t;
        if (i < NBINS * 16) gcur[i] = 0;
    }
}

// ---------------------------------------------------------------------------
// Two-pass binned bucket build (round-5 evidence: returning device atomics cap
// at ~16G/s; this uses ~100k global atomics + LDS-local contention).
// Pass 1: coarse-bin edges by dst>>7, packing (dstLow<<16)|src.
// ---------------------------------------------------------------------------
__global__ __launch_bounds__(256) void pass1_bin(const int* __restrict__ src,
                                                 const int* __restrict__ dst,
                                                 int* __restrict__ gcur,
                                                 int* __restrict__ binned)
{
    __shared__ int hist[NBINS];
    __shared__ int base[NBINS];
    const int t  = threadIdx.x;
    const int e0 = blockIdx.x * EPB;

    for (int b = t; b < NBINS; b += 256) hist[b] = 0;
    __syncthreads();

    for (int e = e0 + t; e < e0 + EPB; e += 256)
        atomicAdd(&hist[dst[e] >> 7], 1);
    __syncthreads();

    for (int b = t; b < NBINS; b += 256) {
        const int c = hist[b];
        base[b] = (c > 0) ? atomicAdd(&gcur[b << 4], c) : 0;
        hist[b] = 0;                       // reuse as local cursor
    }
    __syncthreads();

    for (int e = e0 + t; e < e0 + EPB; e += 256) {
        const int d   = dst[e];
        const int bin = d >> 7;
        const int pos = base[bin] + atomicAdd(&hist[bin], 1);
        if (pos < BINCAP)
            binned[bin * BINCAP + pos] = ((d & 127) << 16) | src[e];
    }
}

// Pass 2: one block per bin (128 nodes); LDS cursors claim per-node slots.
__global__ __launch_bounds__(256) void pass2_scatter(const int* __restrict__ gcur,
                                                     const int* __restrict__ binned,
                                                     int* __restrict__ csrc,
                                                     int* __restrict__ deg)
{
    __shared__ int ncnt[128];
    const int bin = blockIdx.x;
    const int t   = threadIdx.x;
    const int n0  = bin << 7;
    const int cnt = min(gcur[bin << 4], BINCAP);

    if (t < 128) ncnt[t] = 0;
    __syncthreads();

    const int* __restrict__ bb = binned + bin * BINCAP;
    for (int i = t; i < cnt; i += 256) {
        const int v    = bb[i];
        const int dlow = v >> 16;
        const int s    = v & 0xffff;
        const int pos  = atomicAdd(&ncnt[dlow], 1);
        if (pos < CAP) csrc[(size_t)(n0 + dlow) * CAP + pos] = s;
    }
    __syncthreads();

    if (t < 128 && n0 + t < N_NODES) deg[n0 + t] = min(ncnt[t], CAP);
}

// ---------------------------------------------------------------------------
// Fused layer: phase 1 gathers neighbor sums for this block's 64 rows into a
// padded LDS tile (bf16); phase 2 MFMAs Hout = relu([h | agg] @ B[192,96]).
// Phase 1: 6 threads/row x 32B; unroll 4 edges -> 8 loads in flight.
// Phase 2: mfma_f32_16x16x32_bf16, A-frag A[m=lane&15][k=quad*8+j], C/D
// col=lane&15,row=quad*4+reg (m89-verified).  LPAD=104 spreads the ds_read_b128
// bank-starts (m*20%32) over all 32 banks -> bandwidth-optimal LDS reads.
// ---------------------------------------------------------------------------
__global__ __launch_bounds__(384) void gnn_layer(
    const unsigned short* __restrict__ harr, const int* __restrict__ deg,
    const int* __restrict__ csrc, const unsigned short* __restrict__ Btl,
    unsigned short* __restrict__ hout)
{
    __shared__ unsigned short aggLds[64][LPAD];
    const int t       = threadIdx.x;
    const int rowBase = blockIdx.x * 64;

    // ---- phase 1: gather ----
    {
        const int r    = t / 6;          // 0..63
        const int sub  = t - r * 6;      // 0..5
        const int node = rowBase + r;
        const int off  = sub * 16;       // 16 bf16 = 32B per thread

        float a[16];
#pragma unroll
        for (int i = 0; i < 16; i++) a[i] = 0.f;

        if (node < N_NODES) {
            const int d = deg[node];
            const int* __restrict__ bkt = csrc + (size_t)node * CAP;
            const unsigned short* __restrict__ hb = harr + off;

            const int nfull = d & ~3;
            int c = 0;
            for (; c < nfull; c += 4) {
                const int4 s = *(const int4*)(bkt + c);
                const unsigned short* p0 = hb + (size_t)s.x * DIM;
                const unsigned short* p1 = hb + (size_t)s.y * DIM;
                const unsigned short* p2 = hb + (size_t)s.z * DIM;
                const unsigned short* p3 = hb + (size_t)s.w * DIM;
                const u16x8 va0 = *(const u16x8*)(p0), vb0 = *(const u16x8*)(p0 + 8);
                const u16x8 va1 = *(const u16x8*)(p1), vb1 = *(const u16x8*)(p1 + 8);
                const u16x8 va2 = *(const u16x8*)(p2), vb2 = *(const u16x8*)(p2 + 8);
                const u16x8 va3 = *(const u16x8*)(p3), vb3 = *(const u16x8*)(p3 + 8);
#pragma unroll
                for (int i = 0; i < 8; i++) {
                    a[i]     += b2f(va0[i]) + b2f(va1[i]) + b2f(va2[i]) + b2f(va3[i]);
                    a[i + 8] += b2f(vb0[i]) + b2f(vb1[i]) + b2f(vb2[i]) + b2f(vb3[i]);
                }
            }
            for (; c < d; c++) {
                const unsigned short* p0 = hb + (size_t)bkt[c] * DIM;
                const u16x8 va0 = *(const u16x8*)(p0), vb0 = *(const u16x8*)(p0 + 8);
#pragma unroll
                for (int i = 0; i < 8; i++) {
                    a[i]     += b2f(va0[i]);
                    a[i + 8] += b2f(vb0[i]);
                }
            }
        }

        u16x8 o0, o1;
#pragma unroll
        for (int i = 0; i < 8; i++) { o0[i] = f2b(a[i]); o1[i] = f2b(a[i + 8]); }
        *(u16x8*)(&aggLds[r][off])     = o0;
        *(u16x8*)(&aggLds[r][off + 8]) = o1;
    }
    __syncthreads();

    // ---- phase 2: MFMA ----
    const int lane = t & 63;
    const int w    = t >> 6;    // 0..5 col tile
    const int m    = lane & 15;
    const int q    = lane >> 4;

    short8 bfrag[6];
#pragma unroll
    for (int s = 0; s < 6; s++)
        bfrag[s] = *(const short8*)(Btl + (size_t)(w * 16 + m) * (2 * DIM) + s * 32 + q * 8);

#pragma unroll
    for (int r = 0; r < 4; r++) {
        const int rb = rowBase + r * 16;
        f32x4 acc = {0.f, 0.f, 0.f, 0.f};
        const unsigned short* ah = harr + (size_t)(rb + m) * DIM + q * 8;
#pragma unroll
        for (int s = 0; s < 3; s++) {
            const short8 af = *(const short8*)(ah + s * 32);
            acc = __builtin_amdgcn_mfma_f32_16x16x32_bf16(af, bfrag[s], acc, 0, 0, 0);
        }
#pragma unroll
        for (int s = 0; s < 3; s++) {
            const short8 af = *(const short8*)(&aggLds[r * 16 + m][s * 32 + q * 8]);
            acc = __builtin_amdgcn_mfma_f32_16x16x32_bf16(af, bfrag[s + 3], acc, 0, 0, 0);
        }
#pragma unroll
        for (int i = 0; i < 4; i++) {
            const int grow = rb + q * 4 + i;
            if (grow < N_NODES)
                hout[(size_t)grow * DIM + w * 16 + m] = f2b(fmaxf(acc[i], 0.f));
        }
    }
}

// ---------------------------------------------------------------------------
// Fused pool + classifier: graph g's pooled embedding only feeds graph g's
// classifier row -> one block does both.  batch sorted -> contiguous range.
// ---------------------------------------------------------------------------
__global__ __launch_bounds__(384) void pool_classify(
    const unsigned short* __restrict__ h, const int* __restrict__ batch,
    const float* __restrict__ cw1, const float* __restrict__ cb1,
    const float* __restrict__ cw2, const float* __restrict__ cb2,
    float* __restrict__ out)
{
    const int g = blockIdx.x;
    const int t = threadIdx.x;

    int lo = 0, hi = N_NODES;
    while (lo < hi) { int m = (lo + hi) >> 1; if (batch[m] < g) lo = m + 1; else hi = m; }
    const int start = lo;
    hi = N_NODES;
    while (lo < hi) { int m = (lo + hi) >> 1; if (batch[m] < g + 1) lo = m + 1; else hi = m; }
    const int end = lo;

    __shared__ float part[4][DIM];
    __shared__ float gr[DIM];
    __shared__ float hid[DIM];

    const int col = t % DIM;     // 0..95
    const int ty  = t / DIM;     // 0..3

    // pool
    float s = 0.f;
    for (int n = start + ty; n < end; n += 4)
        s += b2f(h[(size_t)n * DIM + col]);
    part[ty][col] = s;
    __syncthreads();
    if (ty == 0)
        gr[col] = part[0][col] + part[1][col] + part[2][col] + part[3][col];
    __syncthreads();

    // hidden = relu(gr @ cw1 + cb1): k split 4-ways across ty
    float hsum = 0.f;
    const int k0 = ty * (DIM / 4);
#pragma unroll 4
    for (int k = k0; k < k0 + DIM / 4; k++)
        hsum += gr[k] * cw1[k * DIM + col];
    part[ty][col] = hsum;
    __syncthreads();
    if (ty == 0)
        hid[col] = fmaxf(part[0][col] + part[1][col] + part[2][col] + part[3][col]
                         + cb1[col], 0.f);
    __syncthreads();

    // out = hid @ cw2 + cb2
    if (t < OUT_DIM) {
        float o = cb2[t];
#pragma unroll 4
        for (int k = 0; k < DIM; k++) o += hid[k] * cw2[k * OUT_DIM + t];
        out[g * OUT_DIM + t] = o;
    }
}

// ---------------------------------------------------------------------------
extern "C" void kernel_launch(void* const* d_in, const int* in_sizes, int n_in,
                              void* d_out, int out_size, void* d_ws, size_t ws_size,
                              hipStream_t stream)
{
    const float* x     = (const float*)d_in[0];
    const int*   ei    = (const int*)  d_in[1];
    const int*   batch = (const int*)  d_in[2];
    const float* W1    = (const float*)d_in[3];
    const float* W2    = (const float*)d_in[4];
    const float* cw1   = (const float*)d_in[5];
    const float* cb1   = (const float*)d_in[6];
    const float* cw2   = (const float*)d_in[7];
    const float* cb2   = (const float*)d_in[8];
    float*       out   = (float*)d_out;

    const int* src = ei;             // edge_index[0]
    const int* dst = ei + N_EDGES;   // edge_index[1]

    // workspace layout (16B-aligned at each boundary)
    unsigned short* bufA = (unsigned short*)d_ws;          // [NPAD,96] bf16
    unsigned short* bufB = bufA + (size_t)NPAD * DIM;      // [NPAD,96] bf16
    unsigned short* Bt   = bufB + (size_t)NPAD * DIM;      // [3,96,192] bf16
    int*   gcur   = (int*)(Bt + 3 * DIM * 2 * DIM);        // [NBINS*16] line-padded
    int*   binned = gcur + NBINS * 16;                     // [NBINS*BINCAP]
    int*   csrc   = binned + (size_t)NBINS * BINCAP;       // [N*CAP]
    int*   deg    = csrc + (size_t)N_NODES * CAP;          // [N]

    prep<<<CAST_NB + CONV_NB + ZERO_NB, 256, 0, stream>>>(x, W1, W2, bufA, Bt, gcur);
    pass1_bin<<<P1_BLOCKS, 256, 0, stream>>>(src, dst, gcur, binned);
    pass2_scatter<<<NBINS, 256, 0, stream>>>(gcur, binned, csrc, deg);

    unsigned short* hin  = bufA;
    unsigned short* hout = bufB;
    for (int l = 0; l < 3; l++) {
        gnn_layer<<<NPAD / 64, 384, 0, stream>>>(hin, deg, csrc,
                                                 Bt + (size_t)l * DIM * 2 * DIM, hout);
        unsigned short* tmp = hin; hin = hout; hout = tmp;
    }

    pool_classify<<<N_GRAPHS, 384, 0, stream>>>(hin, batch, cw1, cb1, cw2, cb2, out);
}